// Round 7
// baseline (661.901 us; speedup 1.0000x reference)
//
#include <hip/hip_runtime.h>

typedef unsigned short u16;
typedef __bf16 bf16x8 __attribute__((ext_vector_type(8)));
typedef float f32x4 __attribute__((ext_vector_type(4)));

__device__ inline float bf2f(u16 u) {
    unsigned int x = ((unsigned int)u) << 16;
    return __builtin_bit_cast(float, x);
}
__device__ inline u16 f2bf(float f) {
    unsigned int x = __builtin_bit_cast(unsigned int, f);
    return (u16)((x + 0x7FFFu + ((x >> 16) & 1u)) >> 16);
}
__device__ inline float sigm(float v) { return 1.f / (1.f + __expf(-v)); }

// load 8 contiguous elements as bf16x8 packed in a uint4.
__device__ inline uint4 load8(const u16* p) { return *(const uint4*)p; }
__device__ inline uint4 load8(const float* p) {
    const float4* q = (const float4*)p;
    float4 a = q[0], b = q[1];
    union { u16 h[8]; uint4 v; } u;
    u.h[0] = f2bf(a.x); u.h[1] = f2bf(a.y); u.h[2] = f2bf(a.z); u.h[3] = f2bf(a.w);
    u.h[4] = f2bf(b.x); u.h[5] = f2bf(b.y); u.h[6] = f2bf(b.z); u.h[7] = f2bf(b.w);
    return u.v;
}

// ---------------------------------------------------------------------------
// MFMA NT GEMM: C[M,N] = A[M,K]*B[N,K]^T; sources fp32-or-bf16 (K-contig),
// converted to bf16 in LDS staging; fp32 accum. 128x128 tile, BK=32,
// 4 waves each 64x64 (4x4 MFMA 16x16x32). M%128==0, K%32==0; N guarded.
// EPI: 0 none; 2 = silu on cols >= 2048 (res half). OUTF32: fp32 vs bf16 out.
// Value-validated: R6 oracle (VALU twin) + R3==R4 bit-identical observable.
// ---------------------------------------------------------------------------
template<typename TA, typename TB, int EPI, bool OUTF32>
__global__ __launch_bounds__(256, 2)
void gemm_bt(const TA* __restrict__ A, int lda,
             const TB* __restrict__ B, int ldb,
             void* __restrict__ Cout, int ldc,
             int M, int N, int K)
{
    __shared__ u16 sA[128][40];   // +8 pad: 16B-aligned rows, 2-way banks (free)
    __shared__ u16 sB[128][40];

    const int tid  = threadIdx.x;
    const int lane = tid & 63;
    const int wave = tid >> 6;
    const int wm = (wave >> 1) * 64;
    const int wn = (wave & 1) * 64;
    const int m0 = blockIdx.y * 128;
    const int n0 = blockIdx.x * 128;
    const int lm = lane & 15;
    const int kq = (lane >> 4) * 8;

    f32x4 acc[4][4] = {};

    for (int kb = 0; kb < K; kb += 32) {
        #pragma unroll
        for (int s = 0; s < 2; ++s) {
            int c = tid + s * 256;          // 0..511
            int r = c >> 2;
            int q = (c & 3) * 8;
            *(uint4*)&sA[r][q] = load8(A + (size_t)(m0 + r) * lda + kb + q);
            uint4 vb = make_uint4(0u, 0u, 0u, 0u);
            if (n0 + r < N)
                vb = load8(B + (size_t)(n0 + r) * ldb + kb + q);
            *(uint4*)&sB[r][q] = vb;
        }
        __syncthreads();

        bf16x8 af[4], bfr[4];
        #pragma unroll
        for (int i = 0; i < 4; ++i)
            af[i] = *(const bf16x8*)&sA[wm + i * 16 + lm][kq];
        #pragma unroll
        for (int j = 0; j < 4; ++j)
            bfr[j] = *(const bf16x8*)&sB[wn + j * 16 + lm][kq];
        #pragma unroll
        for (int i = 0; i < 4; ++i)
            #pragma unroll
            for (int j = 0; j < 4; ++j)
                acc[i][j] = __builtin_amdgcn_mfma_f32_16x16x32_bf16(af[i], bfr[j], acc[i][j], 0, 0, 0);
        __syncthreads();
    }

    // C/D layout: col = lane&15, row = (lane>>4)*4 + reg  [m89/m91-verified]
    #pragma unroll
    for (int i = 0; i < 4; ++i) {
        int crow = m0 + wm + i * 16 + (lane >> 4) * 4;
        #pragma unroll
        for (int j = 0; j < 4; ++j) {
            int ccol = n0 + wn + j * 16 + lm;
            if (ccol < N) {
                #pragma unroll
                for (int r = 0; r < 4; ++r) {
                    float v = acc[i][j][r];
                    if (EPI == 2 && ccol >= 2048) v *= sigm(v);   // silu(res)
                    size_t off = (size_t)(crow + r) * ldc + ccol;
                    if (OUTF32) ((float*)Cout)[off] = v;
                    else        ((u16*)Cout)[off]   = f2bf(v);
                }
            }
        }
    }
}

// ---------------------------------------------------------------------------
// Causal depthwise conv1d (k=4) + bias + SiLU on xr cols [0,2048) -> xs bf16.
// ---------------------------------------------------------------------------
__global__ __launch_bounds__(256)
void conv_silu(const u16* __restrict__ xr, const float* __restrict__ w,
               const float* __restrict__ bias, u16* __restrict__ xs)
{
    int idx = blockIdx.x * 256 + threadIdx.x;       // b*2^21 + t*2^11 + d
    int d = idx & 2047, t = (idx >> 11) & 1023, b = idx >> 21;
    const u16* base = xr + (size_t)b * 1024 * 4096;
    float acc = bias[d];
    #pragma unroll
    for (int j = 0; j < 4; ++j) {
        int ti = t - 3 + j;
        if (ti >= 0) acc = fmaf(w[d * 4 + j], bf2f(base[(size_t)ti * 4096 + d]), acc);
    }
    xs[idx] = f2bf(acc * sigm(acc));
}

// ---------------------------------------------------------------------------
// Fused dt-proj + softplus + selective scan + gating.
// Thread = (b,d,n): n=tid&15, dl=tid>>4. Block covers 16 d's, 64-t chunks.
// yg written IN-PLACE over xs (LDS-staged per chunk; block-private columns).
// Value-validated by R6 oracle (materialized-delta twin gave identical obs).
// ---------------------------------------------------------------------------
__global__ __launch_bounds__(256)
void scan_fused(u16* __restrict__ xs_io, const u16* __restrict__ xdbl,
                const float* __restrict__ A_log, const u16* __restrict__ xr,
                const float* __restrict__ dtw, const float* __restrict__ dtb)
{
    const int tid = threadIdx.x;
    const int n = tid & 15, dl = tid >> 4;
    const int d0 = blockIdx.x * 16, b = blockIdx.y, d = d0 + dl;
    const float Areg = -__expf(A_log[d * 16 + n]);
    float h = 0.f;

    __shared__ float s_dtw[16][68];
    __shared__ float s_dt[64][68];
    __shared__ float s_delta[64][16];
    __shared__ float s_y[64][16];
    __shared__ u16 s_u[64][16], s_B[64][16], s_C[64][16], s_res[64][16];

    for (int idx = tid; idx < 1024; idx += 256) {
        int r = idx >> 6, k = idx & 63;
        s_dtw[r][k] = dtw[(d0 + r) * 64 + k];
    }
    const size_t tok0 = (size_t)b * 1024;

    for (int t0 = 0; t0 < 1024; t0 += 64) {
        for (int idx = tid; idx < 1024; idx += 256) {
            int tl = idx >> 4, j = idx & 15;
            size_t tok = tok0 + t0 + tl;
            s_u[tl][j]   = xs_io[tok * 2048 + d0 + j];
            s_B[tl][j]   = xdbl[tok * 96 + 64 + j];
            s_C[tl][j]   = xdbl[tok * 96 + 80 + j];
            s_res[tl][j] = xr[tok * 4096 + 2048 + d0 + j];   // silu pre-applied
        }
        for (int idx = tid; idx < 4096; idx += 256) {
            int tl = idx >> 6, k = idx & 63;
            s_dt[tl][k] = bf2f(xdbl[(tok0 + t0 + tl) * 96 + k]);
        }
        __syncthreads();

        for (int idx = tid; idx < 1024; idx += 256) {
            int tl = idx >> 4, j = idx & 15;
            float acc = dtb[d0 + j];
            #pragma unroll
            for (int k = 0; k < 64; ++k)
                acc = fmaf(s_dt[tl][k], s_dtw[j][k], acc);
            s_delta[tl][j] = (acc > 20.f) ? acc : log1pf(__expf(acc));
        }
        __syncthreads();

        #pragma unroll 4
        for (int tl = 0; tl < 64; ++tl) {
            float dlt = s_delta[tl][dl];
            float uu = bf2f(s_u[tl][dl]);
            float Bv = bf2f(s_B[tl][n]);
            float Cv = bf2f(s_C[tl][n]);
            h = fmaf(__expf(dlt * Areg), h, dlt * uu * Bv);
            float p = h * Cv;
            p += __shfl_xor(p, 1, 16);
            p += __shfl_xor(p, 2, 16);
            p += __shfl_xor(p, 4, 16);
            p += __shfl_xor(p, 8, 16);
            if (n == 0) s_y[tl][dl] = p * bf2f(s_res[tl][dl]);
        }
        __syncthreads();
        for (int idx = tid; idx < 1024; idx += 256) {
            int tl = idx >> 4, j = idx & 15;
            xs_io[(tok0 + t0 + tl) * 2048 + d0 + j] = f2bf(s_y[tl][j]);
        }
        __syncthreads();
    }
}

__global__ void sentinel_kernel(float* out, float v) { out[0] = v; }

// ---------------------------------------------------------------------------
extern "C" void kernel_launch(void* const* d_in, const int* in_sizes, int n_in,
                              void* d_out, int out_size, void* d_ws, size_t ws_size,
                              hipStream_t stream)
{
    const float* x         = (const float*)d_in[0];   // (2,1024,1024)
    const float* in_w      = (const float*)d_in[1];   // (4096,1024)
    const float* conv_w    = (const float*)d_in[2];   // (2048,1,4)
    const float* conv_b    = (const float*)d_in[3];   // (2048,)
    const float* xproj_w   = (const float*)d_in[4];   // (96,2048)
    const float* dtproj_w  = (const float*)d_in[5];   // (2048,64)
    const float* dtproj_b  = (const float*)d_in[6];   // (2048,)
    const float* A_log     = (const float*)d_in[7];   // (2048,16)
    const float* outproj_w = (const float*)d_in[8];   // (1024,2048)
    float* out = (float*)d_out;                       // fp32 per reference output

    // host-side contract sentinel (codes >= 131072 decode a mismatch)
    static const int EXP[9] = {2097152, 4194304, 8192, 2048, 196608, 131072, 2048, 32768, 2097152};
    int bad = -1;
    if (n_in != 9) bad = 9;
    else { for (int i = 0; i < 9; ++i) if (in_sizes[i] != EXP[i]) { bad = i; break; } }
    if (bad < 0 && out_size != 2097152) bad = 10;
    if (bad < 0 && ws_size < 25559040u) bad = 11;
    if (bad >= 0) {
        sentinel_kernel<<<1, 1, 0, stream>>>(out, 131072.f * (1.f + (float)bad / 16.f));
        return;
    }

    // workspace: 24.4 MiB bf16 intermediates
    char* ws = (char*)d_ws;
    u16* xr   = (u16*)(ws);               // [2048][4096] (xs_pre | silu(res))
    u16* xs   = (u16*)(ws + 16777216);    // [2048][2048] (yg in-place)
    u16* xdbl = (u16*)(ws + 25165824);    // [2048][96]   (dt|B|C)

    // 1) xr = x @ in_proj_w^T (+ silu on res half)
    gemm_bt<float, float, 2, false><<<dim3(32, 16), 256, 0, stream>>>(
        x, 1024, in_w, 1024, xr, 4096, 2048, 4096, 1024);
    // 2) causal conv(k=4) + bias + silu -> xs
    conv_silu<<<16384, 256, 0, stream>>>(xr, conv_w, conv_b, xs);
    // 3) x_dbl = xs @ x_proj_w^T
    gemm_bt<u16, float, 0, false><<<dim3(1, 16), 256, 0, stream>>>(
        xs, 2048, xproj_w, 2048, xdbl, 96, 2048, 96, 2048);
    // 4) fused dt-proj + softplus + scan + gate -> yg (in-place over xs)
    scan_fused<<<dim3(128, 2), 256, 0, stream>>>(xs, xdbl, A_log, xr, dtproj_w, dtproj_b);
    // 5) out = yg @ out_proj_w^T  -> FP32 output
    gemm_bt<u16, float, 0, true><<<dim3(8, 16), 256, 0, stream>>>(
        xs, 2048, outproj_w, 2048, out, 1024, 2048, 1024, 2048);
}

// Round 8
// 362.061 us; speedup vs baseline: 1.8281x; 1.8281x over previous
//
#include <hip/hip_runtime.h>

typedef unsigned short u16;
typedef __bf16 bf16x8 __attribute__((ext_vector_type(8)));
typedef float f32x4 __attribute__((ext_vector_type(4)));

__device__ inline float bf2f(u16 u) {
    unsigned int x = ((unsigned int)u) << 16;
    return __builtin_bit_cast(float, x);
}
__device__ inline u16 f2bf(float f) {
    unsigned int x = __builtin_bit_cast(unsigned int, f);
    return (u16)((x + 0x7FFFu + ((x >> 16) & 1u)) >> 16);
}
__device__ inline float sigm(float v) { return 1.f / (1.f + __expf(-v)); }

__device__ inline uint4 load8(const u16* p) { return *(const uint4*)p; }
__device__ inline uint4 load8(const float* p) {
    const float4* q = (const float4*)p;
    float4 a = q[0], b = q[1];
    union { u16 h[8]; uint4 v; } u;
    u.h[0] = f2bf(a.x); u.h[1] = f2bf(a.y); u.h[2] = f2bf(a.z); u.h[3] = f2bf(a.w);
    u.h[4] = f2bf(b.x); u.h[5] = f2bf(b.y); u.h[6] = f2bf(b.z); u.h[7] = f2bf(b.w);
    return u.v;
}

// ---------------------------------------------------------------------------
// MFMA NT GEMM: C[M,N]=A[M,K]*B[N,K]^T; fp32/bf16 sources -> bf16 LDS; fp32 acc.
// 128x128 tile, BK=32, 4 waves x (64x64). M%128==0, K%32==0; N guarded.
// EPI: 0 none; 1 softplus(acc+bias[col]); 2 silu on cols>=2048.
// ---------------------------------------------------------------------------
template<typename TA, typename TB, int EPI, bool OUTF32>
__global__ __launch_bounds__(256, 2)
void gemm_bt(const TA* __restrict__ A, int lda,
             const TB* __restrict__ B, int ldb,
             void* __restrict__ Cout, int ldc,
             int M, int N, int K, const float* __restrict__ bias)
{
    __shared__ u16 sA[128][40];
    __shared__ u16 sB[128][40];

    const int tid  = threadIdx.x;
    const int lane = tid & 63;
    const int wave = tid >> 6;
    const int wm = (wave >> 1) * 64;
    const int wn = (wave & 1) * 64;
    const int m0 = blockIdx.y * 128;
    const int n0 = blockIdx.x * 128;
    const int lm = lane & 15;
    const int kq = (lane >> 4) * 8;

    f32x4 acc[4][4] = {};

    for (int kb = 0; kb < K; kb += 32) {
        #pragma unroll
        for (int s = 0; s < 2; ++s) {
            int c = tid + s * 256;
            int r = c >> 2;
            int q = (c & 3) * 8;
            *(uint4*)&sA[r][q] = load8(A + (size_t)(m0 + r) * lda + kb + q);
            uint4 vb = make_uint4(0u, 0u, 0u, 0u);
            if (n0 + r < N)
                vb = load8(B + (size_t)(n0 + r) * ldb + kb + q);
            *(uint4*)&sB[r][q] = vb;
        }
        __syncthreads();

        bf16x8 af[4], bfr[4];
        #pragma unroll
        for (int i = 0; i < 4; ++i)
            af[i] = *(const bf16x8*)&sA[wm + i * 16 + lm][kq];
        #pragma unroll
        for (int j = 0; j < 4; ++j)
            bfr[j] = *(const bf16x8*)&sB[wn + j * 16 + lm][kq];
        #pragma unroll
        for (int i = 0; i < 4; ++i)
            #pragma unroll
            for (int j = 0; j < 4; ++j)
                acc[i][j] = __builtin_amdgcn_mfma_f32_16x16x32_bf16(af[i], bfr[j], acc[i][j], 0, 0, 0);
        __syncthreads();
    }

    // C/D layout: col = lane&15, row = (lane>>4)*4 + reg  [m89/m91-verified]
    #pragma unroll
    for (int i = 0; i < 4; ++i) {
        int crow = m0 + wm + i * 16 + (lane >> 4) * 4;
        #pragma unroll
        for (int j = 0; j < 4; ++j) {
            int ccol = n0 + wn + j * 16 + lm;
            if (ccol < N) {
                #pragma unroll
                for (int r = 0; r < 4; ++r) {
                    float v = acc[i][j][r];
                    if (EPI == 1) { v += bias[ccol]; v = (v > 20.f) ? v : log1pf(__expf(v)); }
                    if (EPI == 2 && ccol >= 2048) v *= sigm(v);
                    size_t off = (size_t)(crow + r) * ldc + ccol;
                    if (OUTF32) ((float*)Cout)[off] = v;
                    else        ((u16*)Cout)[off]   = f2bf(v);
                }
            }
        }
    }
}

// ---------------------------------------------------------------------------
// Split-K x_proj GEMM: xdbl_part[z] = xs[:, z*256:(z+1)*256] @ xproj_w^T slice.
// Grid (1, M/128, 8). fp32 slice output [8][2048][96]; reduced by reduce96.
// ---------------------------------------------------------------------------
__global__ __launch_bounds__(256, 2)
void gemm_xproj_splitk(const u16* __restrict__ A, const float* __restrict__ B,
                       float* __restrict__ splits)
{
    __shared__ u16 sA[128][40];
    __shared__ u16 sB[128][40];

    const int tid  = threadIdx.x;
    const int lane = tid & 63;
    const int wave = tid >> 6;
    const int wm = (wave >> 1) * 64;
    const int wn = (wave & 1) * 64;
    const int m0 = blockIdx.y * 128;
    const int z  = blockIdx.z;
    const int lm = lane & 15;
    const int kq = (lane >> 4) * 8;

    f32x4 acc[4][4] = {};

    for (int kb = z * 256; kb < z * 256 + 256; kb += 32) {
        #pragma unroll
        for (int s = 0; s < 2; ++s) {
            int c = tid + s * 256;
            int r = c >> 2;
            int q = (c & 3) * 8;
            *(uint4*)&sA[r][q] = load8(A + (size_t)(m0 + r) * 2048 + kb + q);
            uint4 vb = make_uint4(0u, 0u, 0u, 0u);
            if (r < 96)
                vb = load8(B + (size_t)r * 2048 + kb + q);
            *(uint4*)&sB[r][q] = vb;
        }
        __syncthreads();
        bf16x8 af[4], bfr[4];
        #pragma unroll
        for (int i = 0; i < 4; ++i)
            af[i] = *(const bf16x8*)&sA[wm + i * 16 + lm][kq];
        #pragma unroll
        for (int j = 0; j < 4; ++j)
            bfr[j] = *(const bf16x8*)&sB[wn + j * 16 + lm][kq];
        #pragma unroll
        for (int i = 0; i < 4; ++i)
            #pragma unroll
            for (int j = 0; j < 4; ++j)
                acc[i][j] = __builtin_amdgcn_mfma_f32_16x16x32_bf16(af[i], bfr[j], acc[i][j], 0, 0, 0);
        __syncthreads();
    }

    float* out = splits + (size_t)z * 196608;
    #pragma unroll
    for (int i = 0; i < 4; ++i) {
        int crow = m0 + wm + i * 16 + (lane >> 4) * 4;
        #pragma unroll
        for (int j = 0; j < 4; ++j) {
            int ccol = wn + j * 16 + lm;
            if (ccol < 96) {
                #pragma unroll
                for (int r = 0; r < 4; ++r)
                    out[(size_t)(crow + r) * 96 + ccol] = acc[i][j][r];
            }
        }
    }
}

__global__ __launch_bounds__(256)
void reduce96(const float* __restrict__ splits, u16* __restrict__ xdbl)
{
    int i = blockIdx.x * 256 + threadIdx.x;   // < 196608
    float acc = 0.f;
    #pragma unroll
    for (int z = 0; z < 8; ++z) acc += splits[(size_t)z * 196608 + i];
    xdbl[i] = f2bf(acc);
}

// ---------------------------------------------------------------------------
// Causal depthwise conv1d (k=4) + bias + SiLU on xr cols [0,2048) -> xs bf16.
// ---------------------------------------------------------------------------
__global__ __launch_bounds__(256)
void conv_silu(const u16* __restrict__ xr, const float* __restrict__ w,
               const float* __restrict__ bias, u16* __restrict__ xs)
{
    int idx = blockIdx.x * 256 + threadIdx.x;
    int d = idx & 2047, t = (idx >> 11) & 1023, b = idx >> 21;
    const u16* base = xr + (size_t)b * 1024 * 4096;
    float acc = bias[d];
    #pragma unroll
    for (int j = 0; j < 4; ++j) {
        int ti = t - 3 + j;
        if (ti >= 0) acc = fmaf(w[d * 4 + j], bf2f(base[(size_t)ti * 4096 + d]), acc);
    }
    xs[idx] = f2bf(acc * sigm(acc));
}

// ---------------------------------------------------------------------------
// Chunked parallel scan. Thread = one d, h[16] in registers, no shuffles.
// Chunk Tc=32, 32 chunks/batch. Grid (8 d-blocks, 32 chunks, 2 b) = 512 blocks.
// PHC=0 (phase A): from h=0, emit Bacc[16] and S=sum(delta) per (b,c,d).
// PHC=1 (phase C): from h0 (summ buffer), compute y, gate, write yg over xs.
// Uses prod_t exp(dlt_t*A) == exp(A * sum_t dlt_t) for cross-chunk transfer.
// ---------------------------------------------------------------------------
template<int PHC>
__global__ __launch_bounds__(256)
void scan_chunk(const u16* __restrict__ deltag,   // xr cols 0..2047, ld 4096
                u16* __restrict__ xsg,            // u in, yg out (phase C)
                const u16* __restrict__ xdbl,
                const float* __restrict__ A_log,
                const u16* __restrict__ xr,       // res at cols 2048.., ld 4096
                float* __restrict__ summ,         // [2][32][2048][16] f32
                float* __restrict__ ssum)         // [2][32][2048] f32
{
    const int tid = threadIdx.x;
    const int d0 = blockIdx.x * 256;
    const int c  = blockIdx.y;
    const int b  = blockIdx.z;
    const int d  = d0 + tid;
    const int tok0 = b * 1024 + c * 32;

    __shared__ u16 s_del[32][256];
    __shared__ u16 s_uu[32][256];
    __shared__ u16 s_bc[32][32];
    __shared__ u16 s_res[PHC ? 32 : 1][PHC ? 256 : 1];
    __shared__ u16 s_y[PHC ? 32 : 1][PHC ? 256 : 1];

    // stage chunk inputs (uint4 bulk)
    for (int i = tid; i < 1024; i += 256) {
        int tl = i >> 5, v = i & 31;
        size_t tok = (size_t)(tok0 + tl);
        *(uint4*)&s_del[tl][v * 8] = *(const uint4*)&deltag[tok * 4096 + d0 + v * 8];
        *(uint4*)&s_uu[tl][v * 8]  = *(const uint4*)&xsg[tok * 2048 + d0 + v * 8];
        if (PHC)
            *(uint4*)&s_res[tl][v * 8] = *(const uint4*)&xr[tok * 4096 + 2048 + d0 + v * 8];
    }
    for (int i = tid; i < 1024; i += 256) {
        int tl = i >> 5, j = i & 31;
        s_bc[tl][j] = xdbl[(size_t)(tok0 + tl) * 96 + 64 + j];
    }

    // per-thread A and h
    float Ar[16], h[16];
    {
        const float4* Ap = (const float4*)(A_log + (size_t)d * 16);
        #pragma unroll
        for (int q = 0; q < 4; ++q) {
            float4 a = Ap[q];
            Ar[q * 4 + 0] = -__expf(a.x); Ar[q * 4 + 1] = -__expf(a.y);
            Ar[q * 4 + 2] = -__expf(a.z); Ar[q * 4 + 3] = -__expf(a.w);
        }
    }
    if (PHC) {
        const float4* hp = (const float4*)&summ[((size_t)(b * 32 + c) * 2048 + d) * 16];
        #pragma unroll
        for (int q = 0; q < 4; ++q) {
            float4 v = hp[q];
            h[q * 4 + 0] = v.x; h[q * 4 + 1] = v.y; h[q * 4 + 2] = v.z; h[q * 4 + 3] = v.w;
        }
    } else {
        #pragma unroll
        for (int n = 0; n < 16; ++n) h[n] = 0.f;
    }
    __syncthreads();

    float S = 0.f;
    #pragma unroll 4
    for (int tl = 0; tl < 32; ++tl) {
        float dlt = bf2f(s_del[tl][tid]);
        float du = dlt * bf2f(s_uu[tl][tid]);
        if (!PHC) S += dlt;
        #pragma unroll
        for (int n = 0; n < 16; ++n)
            h[n] = fmaf(__expf(dlt * Ar[n]), h[n], du * bf2f(s_bc[tl][n]));
        if (PHC) {
            float y = 0.f;
            #pragma unroll
            for (int n = 0; n < 16; ++n)
                y = fmaf(h[n], bf2f(s_bc[tl][16 + n]), y);
            s_y[tl][tid] = f2bf(y * bf2f(s_res[tl][tid]));
        }
    }

    if (!PHC) {
        float4* bp = (float4*)&summ[((size_t)(b * 32 + c) * 2048 + d) * 16];
        #pragma unroll
        for (int q = 0; q < 4; ++q)
            bp[q] = make_float4(h[q * 4], h[q * 4 + 1], h[q * 4 + 2], h[q * 4 + 3]);
        ssum[(size_t)(b * 32 + c) * 2048 + d] = S;
    } else {
        __syncthreads();
        for (int i = tid; i < 1024; i += 256) {
            int tl = i >> 5, v = i & 31;
            *(uint4*)&xsg[(size_t)(tok0 + tl) * 2048 + d0 + v * 8] = *(uint4*)&s_y[tl][v * 8];
        }
    }
}

// Phase B: sequential over 32 chunk summaries; h0 written in-place over Bacc.
__global__ __launch_bounds__(256)
void scan_phaseB(float* __restrict__ summ, const float* __restrict__ ssum,
                 const float* __restrict__ A_log)
{
    int g = blockIdx.x * 256 + threadIdx.x;   // 65536 threads
    int n = g & 15;
    int d = (g >> 4) & 2047;
    int b = g >> 15;
    float An = -__expf(A_log[(size_t)d * 16 + n]);
    float h = 0.f;
    for (int c = 0; c < 32; ++c) {
        size_t idx = ((size_t)(b * 32 + c) * 2048 + d) * 16 + n;
        float bc = summ[idx];
        float Sc = ssum[(size_t)(b * 32 + c) * 2048 + d];
        summ[idx] = h;                       // h0 for chunk c
        h = fmaf(__expf(An * Sc), h, bc);
    }
}

__global__ void sentinel_kernel(float* out, float v) { out[0] = v; }

// ---------------------------------------------------------------------------
extern "C" void kernel_launch(void* const* d_in, const int* in_sizes, int n_in,
                              void* d_out, int out_size, void* d_ws, size_t ws_size,
                              hipStream_t stream)
{
    const float* x         = (const float*)d_in[0];   // (2,1024,1024)
    const float* in_w      = (const float*)d_in[1];   // (4096,1024)
    const float* conv_w    = (const float*)d_in[2];   // (2048,1,4)
    const float* conv_b    = (const float*)d_in[3];   // (2048,)
    const float* xproj_w   = (const float*)d_in[4];   // (96,2048)
    const float* dtproj_w  = (const float*)d_in[5];   // (2048,64)
    const float* dtproj_b  = (const float*)d_in[6];   // (2048,)
    const float* A_log     = (const float*)d_in[7];   // (2048,16)
    const float* outproj_w = (const float*)d_in[8];   // (1024,2048)
    float* out = (float*)d_out;                       // fp32 output

    static const int EXP[9] = {2097152, 4194304, 8192, 2048, 196608, 131072, 2048, 32768, 2097152};
    int bad = -1;
    if (n_in != 9) bad = 9;
    else { for (int i = 0; i < 9; ++i) if (in_sizes[i] != EXP[i]) { bad = i; break; } }
    if (bad < 0 && out_size != 2097152) bad = 10;
    if (bad < 0 && ws_size < 34471936u) bad = 11;    // high-water mark
    if (bad >= 0) {
        sentinel_kernel<<<1, 1, 0, stream>>>(out, 131072.f * (1.f + (float)bad / 16.f));
        return;
    }

    // ws map: xr 16M | xs 8M | xdbl .38M | region X (splits 6.3M, then summ 8M + ssum .5M)
    char* ws = (char*)d_ws;
    u16*   xr     = (u16*)(ws);               // [2048][4096]; cols<2048: xs_pre then delta; >=2048: silu(res)
    u16*   xs     = (u16*)(ws + 16777216);    // [2048][2048] u -> yg in-place
    u16*   xdbl   = (u16*)(ws + 25165824);    // [2048][96]
    float* splits = (float*)(ws + 25559040);  // [8][2048][96] f32 (transient)
    float* summ   = (float*)(ws + 25559040);  // [2][32][2048][16] f32 (after splits dead)
    float* ssum   = (float*)(ws + 33947648);  // [2][32][2048] f32 -> ends 34471936

    // 1) in_proj (+silu on res half)
    gemm_bt<float, float, 2, false><<<dim3(32, 16), 256, 0, stream>>>(
        x, 1024, in_w, 1024, xr, 4096, 2048, 4096, 1024, nullptr);
    // 2) conv + silu -> xs
    conv_silu<<<16384, 256, 0, stream>>>(xr, conv_w, conv_b, xs);
    // 3) x_proj split-K (8) + reduce -> xdbl
    gemm_xproj_splitk<<<dim3(1, 16, 8), 256, 0, stream>>>(xs, xproj_w, splits);
    reduce96<<<768, 256, 0, stream>>>(splits, xdbl);
    // 4) delta = softplus(xdbl[:, :64] @ dtw^T + dtb) -> xr cols [0,2048) (dead xs_pre)
    gemm_bt<u16, float, 1, false><<<dim3(16, 16), 256, 0, stream>>>(
        xdbl, 96, dtproj_w, 64, xr, 4096, 2048, 2048, 64, dtproj_b);
    // 5) chunked scan: A (summaries) -> B (prefix over chunks) -> C (y + gate)
    scan_chunk<0><<<dim3(8, 32, 2), 256, 0, stream>>>(xr, xs, xdbl, A_log, xr, summ, ssum);
    scan_phaseB<<<256, 256, 0, stream>>>(summ, ssum, A_log);
    scan_chunk<1><<<dim3(8, 32, 2), 256, 0, stream>>>(xr, xs, xdbl, A_log, xr, summ, ssum);
    // 6) out = yg @ out_proj_w^T -> fp32
    gemm_bt<u16, float, 0, true><<<dim3(8, 16), 256, 0, stream>>>(
        xs, 2048, outproj_w, 2048, out, 1024, 2048, 1024, 2048, nullptr);
}